// Round 5
// baseline (1508.158 us; speedup 1.0000x reference)
//
#include <hip/hip_runtime.h>
#include <cstdint>
#include <cstddef>

#define N_NODES 100000
#define D 128
#define R 4
#define NE 150000
#define LAYERS 2
#define NROWS (R * N_NODES)   // 400000
#define CAP 16                // max in-degree per (rel,dst); Poisson(1.5) -> P(>16) ~ 1e-12
#define OVFS 12               // overflow slots per row (CAP - 4 inline)
#define TILES (N_NODES / 16)  // 6250
#define GRID 256              // persistent: one block per CU (LDS-capped anyway)
#define TPB 512               // 8 independent waves per block
#define WPB 8
#define NWAVES (GRID * WPB)   // 2048
#define WTL_ELEMS 65536       // per-layer swizzled W: 4*8*4*16*32 bf16 = 128 KB

typedef __attribute__((ext_vector_type(8))) short bf16x8;
typedef __attribute__((ext_vector_type(4))) float f32x4;
typedef __attribute__((ext_vector_type(4))) int i32x4;
typedef __attribute__((ext_vector_type(4))) unsigned short u16x4;

__device__ __forceinline__ unsigned short f2bf(float x) {
  union { float f; unsigned int u; } v; v.f = x;
  unsigned int u = v.u;
  return (unsigned short)((u + 0x7fffu + ((u >> 16) & 1u)) >> 16);  // RNE
}
__device__ __forceinline__ float bf2f(unsigned short u) {
  union { unsigned int i; float f; } v; v.i = ((unsigned int)u) << 16;
  return v.f;
}

// ---- prep1: out-degree count + emb fp32->bf16 + swizzled-W + bmean ------
// WtL layout (per layer, element index p):
//   p = (((r*8+ct)*4+ks)*16 + m)*32 + qq*8 + j,  qq = q ^ ((m>>1)&3)
//   value = W[layer][r][k = ks*32 + q*8 + j][c = ct*16 + m]
// The XOR on q makes the fused kernel's per-(r,ct,ks) ds_read_b128 (lane: m=l&15,
// q=l>>4 reads 16B at m*64 + qq*16) hit 8 distinct 16B slots per 8-lane group.
__global__ void prep1_kernel(const float* __restrict__ emb, const float* __restrict__ W,
                             const float* __restrict__ biases, const int* __restrict__ edges,
                             int* __restrict__ deg_i, unsigned short* __restrict__ hb,
                             unsigned short* __restrict__ WtLg, float* __restrict__ bmean) {
  int t = blockIdx.x * blockDim.x + threadIdx.x;
  if (t < N_NODES * D / 4) {
    f32x4 v = *(const f32x4*)(emb + (size_t)t * 4);
    u16x4 o;
#pragma unroll
    for (int j = 0; j < 4; ++j) o[j] = f2bf(v[j]);
    *(u16x4*)(hb + (size_t)t * 4) = o;
  }
  if (t < NE * R) {
    int r = t / NE;
    int e = t - r * NE;
    int src = edges[(size_t)(r * 2) * NE + e];
    atomicAdd(&deg_i[r * N_NODES + src], 1);
  }
  if (t < LAYERS * WTL_ELEMS) {
    int lr = t >> 16;
    int p = t & 65535;
    int j = p & 7;
    int qq = (p >> 3) & 3;
    int mm = (p >> 5) & 15;
    int ks = (p >> 9) & 3;
    int ct = (p >> 11) & 7;
    int r = (p >> 14) & 3;
    int ql = qq ^ ((mm >> 1) & 3);
    int k = ks * 32 + ql * 8 + j;
    int c = ct * 16 + mm;
    WtLg[((size_t)lr << 16) | p] = f2bf(W[(((size_t)lr * R + r) * D + k) * D + c]);
  }
  if (t < LAYERS * D) {
    int l = t >> 7, cc = t & 127;
    float s = 0.f;
    for (int r = 0; r < R; ++r) s += biases[((size_t)l * R + r) * D + cc];
    bmean[t] = s * 0.25f;
  }
}

// fill padded edge records {src, rsqrt(deg_out[src])}; cursor counts in-degree.
// SoA: slots 0..3 packed per (rel,tile): rec2[r][tile][m][slot] (512 B/tile-rel).
// Slots 4..15 -> ovf[rowg][slot-4]. Neither zeroed: gather masks by cnt.
__global__ void fill_kernel(const int* __restrict__ edges, const int* __restrict__ deg_i,
                            int* __restrict__ cursor, int2* __restrict__ rec2,
                            int2* __restrict__ ovf) {
  int e = blockIdx.x * blockDim.x + threadIdx.x;
  int r = blockIdx.y;
  if (e >= NE) return;
  int src = edges[(size_t)(r * 2) * NE + e];
  int dst = edges[(size_t)(r * 2 + 1) * NE + e];
  float sc = rsqrtf(fmaxf((float)deg_i[r * N_NODES + src], 1.0f));
  int rowg = r * N_NODES + dst;
  int slot = atomicAdd(&cursor[rowg], 1);
  if (slot < 4) {
    int tile = dst >> 4, mm = dst & 15;
    rec2[(((size_t)(r * TILES + tile) * 16 + mm) << 2) + slot] = make_int2(src, __float_as_int(sc));
  } else if (slot < CAP) {
    ovf[(size_t)rowg * OVFS + (slot - 4)] = make_int2(src, __float_as_int(sc));
  }
}

// ---- gather-phase macros. rel loop is STATICALLY unrolled (4 literal iters),
// so all [S]/[RELr] indices are compile-time -> register-allocated (rule #20).
#define LOADREC(S, RELr, TT) do { \
  const int2* rp_ = rec2 + (((size_t)((RELr) * TILES + (TT)) * 16 + m) << 2); \
  cnraw[S] = cnt[(RELr) * N_NODES + (TT) * 16 + m]; \
  rc0[S] = *(const i32x4*)(rp_); \
  rc1[S] = *(const i32x4*)(rp_ + 2); \
} while (0)

#define ISSUE(S, RELr, TT) do { \
  int cn_ = cnraw[S]; \
  sdeg[RELr] = rsqrtf(fmaxf((float)cn_, 1.0f)); \
  int n_ = cn_ > CAP ? CAP : cn_; \
  nn[S] = n_; \
  int a0_ = rc0[S].x, a1_ = rc0[S].z, a2_ = rc1[S].x, a3_ = rc1[S].z; \
  float b0_ = __int_as_float(rc0[S].y), b1_ = __int_as_float(rc0[S].w); \
  float b2_ = __int_as_float(rc1[S].y), b3_ = __int_as_float(rc1[S].w); \
  if (n_ < 1) { a0_ = 0; b0_ = 0.f; } \
  if (n_ < 2) { a1_ = 0; b1_ = 0.f; } \
  if (n_ < 3) { a2_ = 0; b2_ = 0.f; } \
  if (n_ < 4) { a3_ = 0; b3_ = 0.f; } \
  scs[S][0] = b0_; scs[S][1] = b1_; scs[S][2] = b2_; scs[S][3] = b3_; \
  const unsigned short* h0_ = hb + (size_t)a0_ * D + q * 8; \
  const unsigned short* h1_ = hb + (size_t)a1_ * D + q * 8; \
  const unsigned short* h2_ = hb + (size_t)a2_ * D + q * 8; \
  const unsigned short* h3_ = hb + (size_t)a3_ * D + q * 8; \
  _Pragma("unroll") for (int ks_ = 0; ks_ < 4; ++ks_) { \
    ld[S][0 * 4 + ks_] = *(const bf16x8*)(h0_ + ks_ * 32); \
    ld[S][1 * 4 + ks_] = *(const bf16x8*)(h1_ + ks_ * 32); \
    ld[S][2 * 4 + ks_] = *(const bf16x8*)(h2_ + ks_ * 32); \
    ld[S][3 * 4 + ks_] = *(const bf16x8*)(h3_ + ks_ * 32); \
  } \
  if (__builtin_expect(n_ > 4, 0)) \
    tr[S] = *(const i32x4*)(ovf + (size_t)((RELr) * N_NODES + (TT) * 16 + m) * OVFS); \
} while (0)

// accumulate stage S into agg[RELr][0..3], folding the deg_in rsqrt into the
// A-rows BEFORE bf16 (row-scaling commutes with the GEMM).
#define ACCUM(S, RELr, TT) do { \
  float accf[4][8]; \
  _Pragma("unroll") for (int k_ = 0; k_ < 4; ++k_) \
    _Pragma("unroll") for (int j_ = 0; j_ < 8; ++j_) accf[k_][j_] = 0.f; \
  if (__builtin_expect(nn[S] > 4, 0)) { \
    int nf_ = nn[S]; \
    bool ok_ = nf_ > 5; \
    int sA_ = tr[S].x, sB_ = ok_ ? tr[S].z : 0; \
    float cA_ = __int_as_float(tr[S].y), cB_ = ok_ ? __int_as_float(tr[S].w) : 0.f; \
    const unsigned short* hA_ = hb + (size_t)sA_ * D + q * 8; \
    const unsigned short* hB_ = hb + (size_t)sB_ * D + q * 8; \
    _Pragma("unroll") for (int k_ = 0; k_ < 4; ++k_) { \
      bf16x8 x0_ = *(const bf16x8*)(hA_ + k_ * 32); \
      bf16x8 x1_ = *(const bf16x8*)(hB_ + k_ * 32); \
      _Pragma("unroll") for (int j_ = 0; j_ < 8; ++j_) \
        accf[k_][j_] += cA_ * bf2f((unsigned short)x0_[j_]) + cB_ * bf2f((unsigned short)x1_[j_]); \
    } \
    const int2* op_ = ovf + (size_t)((RELr) * N_NODES + (TT) * 16 + m) * OVFS; \
    for (int i_ = 6; i_ < nf_; i_ += 2) { \
      i32x4 rr_ = *(const i32x4*)(op_ + (i_ - 4)); \
      bool o2_ = (i_ + 1) < nf_; \
      int s0_ = rr_.x, s1_ = o2_ ? rr_.z : 0; \
      float d0_ = __int_as_float(rr_.y), d1_ = o2_ ? __int_as_float(rr_.w) : 0.f; \
      const unsigned short* y0_ = hb + (size_t)s0_ * D + q * 8; \
      const unsigned short* y1_ = hb + (size_t)s1_ * D + q * 8; \
      _Pragma("unroll") for (int k_ = 0; k_ < 4; ++k_) { \
        bf16x8 x0_ = *(const bf16x8*)(y0_ + k_ * 32); \
        bf16x8 x1_ = *(const bf16x8*)(y1_ + k_ * 32); \
        _Pragma("unroll") for (int j_ = 0; j_ < 8; ++j_) \
          accf[k_][j_] += d0_ * bf2f((unsigned short)x0_[j_]) + d1_ * bf2f((unsigned short)x1_[j_]); \
      } \
    } \
  } \
  _Pragma("unroll") for (int k_ = 0; k_ < 4; ++k_) \
    _Pragma("unroll") for (int j_ = 0; j_ < 8; ++j_) \
      accf[k_][j_] += scs[S][0] * bf2f((unsigned short)ld[S][0 * 4 + k_][j_]) \
                    + scs[S][1] * bf2f((unsigned short)ld[S][1 * 4 + k_][j_]) \
                    + scs[S][2] * bf2f((unsigned short)ld[S][2 * 4 + k_][j_]) \
                    + scs[S][3] * bf2f((unsigned short)ld[S][3 * 4 + k_][j_]); \
  float sd_ = sdeg[RELr]; \
  _Pragma("unroll") for (int k_ = 0; k_ < 4; ++k_) { \
    union { bf16x8 v; unsigned short s[8]; } u_; \
    _Pragma("unroll") for (int j_ = 0; j_ < 8; ++j_) u_.s[j_] = f2bf(accf[k_][j_] * sd_); \
    agg[RELr][k_] = u_.v; \
  } \
} while (0)

// ======== persistent all-independent-waves fused kernel =====================
// 256 blocks x 8 waves, NO main-loop barriers. Each wave owns whole tiles:
// gather+aggregate all 4 rels in registers (the accumulation layout IS the
// MFMA A-fragment layout: lane l = row l&15, k = ks*32+(l>>4)*8), then MFMA
// against swizzled W held in LDS (128 KB, loaded once). Gather latency is
// hidden by the co-resident wave on the same SIMD, not exposed to 7 others.
__global__ __launch_bounds__(TPB, 2) void fused_kernel(
    const unsigned short* __restrict__ hb,     // [N][128] bf16
    const int2* __restrict__ rec2,             // [R][TILES][16][4] {src, s_out}
    const int2* __restrict__ ovf,              // [NROWS][OVFS] overflow records
    const int* __restrict__ cnt,               // [NROWS] in-degree (may exceed CAP)
    const unsigned short* __restrict__ WtLg,   // layer: swizzled W, 65536 bf16
    const float* __restrict__ bmean,           // [128]
    const unsigned short* __restrict__ resid_bf,
    float* __restrict__ out_f,
    unsigned short* __restrict__ out_bf) {
  __shared__ unsigned short WtL[WTL_ELEMS];  // 128 KB
  {
    const f32x4* s = (const f32x4*)WtLg;
    f32x4* d = (f32x4*)WtL;
#pragma unroll
    for (int i = 0; i < 16; ++i) d[i * TPB + threadIdx.x] = s[i * TPB + threadIdx.x];
  }
  __syncthreads();  // only barrier in the kernel

  const int w = threadIdx.x >> 6;
  const int lane = threadIdx.x & 63;
  const int m = lane & 15;
  const int q = lane >> 4;
  const int gw = blockIdx.x * WPB + w;
  const int moff = m * 64 + ((q ^ ((m >> 1) & 3)) << 4);  // swizzled byte off in 1KB slab

  for (int tile = gw; tile < TILES; tile += NWAVES) {
    // ---- gather/aggregate: 4 rels, 2-deep static pipeline ----
    int cnraw[2], nn[2];
    i32x4 rc0[2], rc1[2], tr[2];
    float scs[2][4], sdeg[R];
    bf16x8 ld[2][16];
    bf16x8 agg[R][4];

    LOADREC(0, 0, tile);
    ISSUE(0, 0, tile);
    LOADREC(1, 1, tile);
#pragma unroll
    for (int rr = 0; rr < R; ++rr) {
      if (rr < R - 1) ISSUE((rr + 1) & 1, rr + 1, tile);
      if (rr < R - 2) LOADREC(rr & 1, rr + 2, tile);
      ACCUM(rr & 1, rr, tile);
    }

    // ---- MFMA + epilogue: 8 col-tiles x (4 rels x 4 ks) ----
#pragma unroll
    for (int ct = 0; ct < 8; ++ct) {
      f32x4 acc = (f32x4){0.f, 0.f, 0.f, 0.f};
#pragma unroll
      for (int r2 = 0; r2 < R; ++r2)
#pragma unroll
        for (int ks = 0; ks < 4; ++ks) {
          bf16x8 b = *(const bf16x8*)((const char*)WtL + (((r2 * 8 + ct) * 4 + ks) << 10) + moff);
          acc = __builtin_amdgcn_mfma_f32_16x16x32_bf16(agg[r2][ks], b, acc, 0, 0, 0);
        }
      int colx = ct * 16 + m;
      float bm = bmean[colx];
#pragma unroll
      for (int i = 0; i < 4; ++i) {
        int row = tile * 16 + q * 4 + i;
        float v = acc[i] * 0.25f + bm;
        v = (v >= 0.f) ? v : 0.2f * v;
        if (resid_bf) v += bf2f(resid_bf[(size_t)row * D + colx]);
        if (out_f) out_f[(size_t)row * D + colx] = v;
        else       out_bf[(size_t)row * D + colx] = f2bf(v);
      }
    }
  }
}

extern "C" void kernel_launch(void* const* d_in, const int* in_sizes, int n_in,
                              void* d_out, int out_size, void* d_ws, size_t ws_size,
                              hipStream_t stream) {
  const float* emb    = (const float*)d_in[0];
  const float* W      = (const float*)d_in[1];
  const float* biases = (const float*)d_in[2];
  const int*   edges  = (const int*)d_in[3];
  float* out = (float*)d_out;
  char* ws = (char*)d_ws;

  size_t off = 0;
  auto alloc = [&](size_t bytes) { size_t o = off; off += (bytes + 255) & ~255ull; return o; };
  // only the int arrays (deg_i | cursor) need zeroing -> 3.2 MB memset
  int* ints      = (int*)(ws + alloc((size_t)2 * NROWS * 4));   // [deg_i | cursor]
  int* deg_i     = ints;
  int* cursor    = ints + NROWS;
  size_t zero_bytes = off;
  int2* rec2     = (int2*)(ws + alloc((size_t)R * TILES * 16 * 4 * 8));  // 12.8 MB, NOT zeroed
  int2* ovf      = (int2*)(ws + alloc((size_t)NROWS * OVFS * 8));        // 38.4 MB, NOT zeroed
  unsigned short* hb  = (unsigned short*)(ws + alloc((size_t)N_NODES * D * 2));
  unsigned short* hb2 = (unsigned short*)(ws + alloc((size_t)N_NODES * D * 2));
  unsigned short* WtLg = (unsigned short*)(ws + alloc((size_t)LAYERS * WTL_ELEMS * 2));
  float* bmean   = (float*)(ws + alloc((size_t)LAYERS * D * 4));
  (void)ws_size;

  // ---- prep: memset -> prep1(count+conversions+swizzle) -> fill ----
  hipMemsetAsync(ws, 0, zero_bytes, stream);
  prep1_kernel<<<(N_NODES * D / 4 + 255) / 256, 256, 0, stream>>>(
      emb, W, biases, edges, deg_i, hb, WtLg, bmean);
  fill_kernel<<<dim3((NE + 255) / 256, R), 256, 0, stream>>>(edges, deg_i, cursor, rec2, ovf);

  // layer 0: emb(bf16) -> hb2(bf16), no residual
  fused_kernel<<<GRID, TPB, 0, stream>>>(
      hb, rec2, ovf, cursor, WtLg, bmean, nullptr, nullptr, hb2);
  // layer 1: hb2 -> out(fp32), residual = hb2
  fused_kernel<<<GRID, TPB, 0, stream>>>(
      hb2, rec2, ovf, cursor, WtLg + WTL_ELEMS, bmean + D, hb2, out, nullptr);
}

// Round 6
// 470.260 us; speedup vs baseline: 3.2071x; 3.2071x over previous
//
#include <hip/hip_runtime.h>
#include <hip/hip_cooperative_groups.h>
#include <cstdint>
#include <cstddef>

namespace cg = cooperative_groups;

#define N_NODES 100000
#define D 128
#define R 4
#define NE 150000
#define LAYERS 2
#define NROWS (R * N_NODES)   // 400000
#define CAP 16                // max in-degree per (rel,dst); Poisson(1.5) -> P(>16) ~ 1e-12
#define OVFS 12               // overflow slots per row (CAP - 4 inline)
#define TILES (N_NODES / 16)  // 6250
#define GRID 256              // one block per CU; cooperative co-residency guaranteed
#define TPB 512               // 8 waves: 4 producers + 4 consumers
#define NTH (GRID * TPB)      // 131072 threads for the prep phases

typedef __attribute__((ext_vector_type(8))) short bf16x8;
typedef __attribute__((ext_vector_type(4))) float f32x4;
typedef __attribute__((ext_vector_type(4))) int i32x4;
typedef __attribute__((ext_vector_type(4))) unsigned short u16x4;

__device__ __forceinline__ unsigned short f2bf(float x) {
  union { float f; unsigned int u; } v; v.f = x;
  unsigned int u = v.u;
  return (unsigned short)((u + 0x7fffu + ((u >> 16) & 1u)) >> 16);  // RNE
}
__device__ __forceinline__ float bf2f(unsigned short u) {
  union { unsigned int i; float f; } v; v.i = ((unsigned int)u) << 16;
  return v.f;
}

// ======== single cooperative mega-kernel ====================================
// Phases (grid.sync between each):
//   Z: zero deg_i|cursor (contiguous)        C: count atomics + emb->bf16 + Wt + bmean
//   F: fill SoA edge records                 L0: layer 0 (hb -> hb2 bf16)
//   L1: layer 1 (hb2 -> out fp32, resid hb2)
// Layer body = R0's proven producer/consumer structure (104 VGPR, no scratch):
// waves 0-3 gather-aggregate one relation each into t_lds[it&1]; waves 4-7
// MFMA+epilogue tile it-1 from t_lds[(it-1)&1]. One __syncthreads per tile.
// NO multi-stage register pipelines (R2/R3/R5 all spilled to scratch).
__global__ __launch_bounds__(TPB, 2) void mega_kernel(
    const float* __restrict__ emb, const float* __restrict__ W,
    const float* __restrict__ biases, const int* __restrict__ edges,
    int* __restrict__ ints,                  // [deg_i | cursor], 2*NROWS
    int2* __restrict__ rec2,                 // [R][TILES][16][4] {src, s_out}
    int2* __restrict__ ovf,                  // [NROWS][OVFS]
    unsigned short* __restrict__ hb,         // [N][128] bf16 (layer-0 input)
    unsigned short* __restrict__ hb2,        // [N][128] bf16 (layer-0 out / layer-1 in+resid)
    unsigned short* __restrict__ Wt,         // [LAYERS*R][128 col][128 k] bf16
    float* __restrict__ bmean,               // [LAYERS][128]
    float* __restrict__ out) {               // [N][128] fp32
  cg::grid_group grid = cg::this_grid();
  int* deg_i = ints;
  int* cursor = ints + NROWS;
  const int tid = blockIdx.x * TPB + threadIdx.x;

  // ---- phase Z: zero deg_i + cursor (contiguous 800000 ints) ----
  for (int i = tid; i < 2 * NROWS; i += NTH) ints[i] = 0;
  grid.sync();

  // ---- phase C: out-degree count + conversions ----
  for (int i = tid; i < NE * R; i += NTH) {
    int r = i / NE, e = i - r * NE;
    atomicAdd(&deg_i[r * N_NODES + edges[(size_t)(r * 2) * NE + e]], 1);
  }
  for (int i = tid; i < N_NODES * D / 4; i += NTH) {
    f32x4 v = *(const f32x4*)(emb + (size_t)i * 4);
    u16x4 o;
#pragma unroll
    for (int j = 0; j < 4; ++j) o[j] = f2bf(v[j]);
    *(u16x4*)(hb + (size_t)i * 4) = o;
  }
  for (int i = tid; i < LAYERS * R * D * D; i += NTH) {
    int k = i & 127, c = (i >> 7) & 127, lr = i >> 14;
    Wt[((size_t)lr << 14) | (c << 7) | k] = f2bf(W[((size_t)lr << 14) | (k << 7) | c]);
  }
  if (tid < LAYERS * D) {
    int l = tid >> 7, cc = tid & 127;
    float s = 0.f;
    for (int r = 0; r < R; ++r) s += biases[((size_t)l * R + r) * D + cc];
    bmean[tid] = s * 0.25f;
  }
  grid.sync();

  // ---- phase F: fill edge records {src, rsqrt(deg_out)}; SoA slots 0-3 ----
  for (int i = tid; i < NE * R; i += NTH) {
    int r = i / NE, e = i - r * NE;
    int src = edges[(size_t)(r * 2) * NE + e];
    int dst = edges[(size_t)(r * 2 + 1) * NE + e];
    float sc = rsqrtf(fmaxf((float)deg_i[r * N_NODES + src], 1.0f));
    int rowg = r * N_NODES + dst;
    int slot = atomicAdd(&cursor[rowg], 1);
    if (slot < 4) {
      rec2[(((size_t)(r * TILES + (dst >> 4)) * 16 + (dst & 15)) << 2) + slot] =
          make_int2(src, __float_as_int(sc));
    } else if (slot < CAP) {
      ovf[(size_t)rowg * OVFS + (slot - 4)] = make_int2(src, __float_as_int(sc));
    }
  }
  grid.sync();

  // ---- layers ----
  __shared__ unsigned short t_lds[2][R * 4 * 64 * 8];  // 2 x 16 KB
  const int w = threadIdx.x >> 6;
  const int lane = threadIdx.x & 63;
  const int m = lane & 15;
  const int q = lane >> 4;
  const int bid = blockIdx.x;
  const int nt = (TILES - bid + GRID - 1) / GRID;
  const int* cnt = cursor;

  for (int L = 0; L < LAYERS; ++L) {
    const unsigned short* hin = L ? hb2 : hb;

    if (w < 4) {
      // -------------------- producer: relation w --------------------
      const int r = w;
      for (int it = 0; it < nt + 1; ++it) {
        if (it < nt) {
          const int tile = bid + it * GRID;
          const int rowg = r * N_NODES + tile * 16 + m;
          const int2* rp = rec2 + (((size_t)(r * TILES + tile) * 16 + m) << 2);
          int cn = cnt[rowg];
          int n = cn > CAP ? CAP : cn;
          i32x4 r01 = *(const i32x4*)rp;
          i32x4 r23 = *(const i32x4*)(rp + 2);
          int s0 = r01.x, s1 = r01.z, s2 = r23.x, s3 = r23.z;
          float c0 = __int_as_float(r01.y), c1 = __int_as_float(r01.w);
          float c2 = __int_as_float(r23.y), c3 = __int_as_float(r23.w);
          // rec pads are garbage: mask (row 0 stays L1-hot)
          if (n < 1) { s0 = 0; c0 = 0.f; }
          if (n < 2) { s1 = 0; c1 = 0.f; }
          if (n < 3) { s2 = 0; c2 = 0.f; }
          if (n < 4) { s3 = 0; c3 = 0.f; }
          const unsigned short* h0 = hin + (size_t)s0 * D + q * 8;
          const unsigned short* h1 = hin + (size_t)s1 * D + q * 8;
          const unsigned short* h2 = hin + (size_t)s2 * D + q * 8;
          const unsigned short* h3 = hin + (size_t)s3 * D + q * 8;
          // all 16 gathers as NAMED vars -> one batch in flight, no scratch
          bf16x8 g0  = *(const bf16x8*)(h0);      bf16x8 g1  = *(const bf16x8*)(h0 + 32);
          bf16x8 g2  = *(const bf16x8*)(h0 + 64); bf16x8 g3  = *(const bf16x8*)(h0 + 96);
          bf16x8 g4  = *(const bf16x8*)(h1);      bf16x8 g5  = *(const bf16x8*)(h1 + 32);
          bf16x8 g6  = *(const bf16x8*)(h1 + 64); bf16x8 g7  = *(const bf16x8*)(h1 + 96);
          bf16x8 g8  = *(const bf16x8*)(h2);      bf16x8 g9  = *(const bf16x8*)(h2 + 32);
          bf16x8 g10 = *(const bf16x8*)(h2 + 64); bf16x8 g11 = *(const bf16x8*)(h2 + 96);
          bf16x8 g12 = *(const bf16x8*)(h3);      bf16x8 g13 = *(const bf16x8*)(h3 + 32);
          bf16x8 g14 = *(const bf16x8*)(h3 + 64); bf16x8 g15 = *(const bf16x8*)(h3 + 96);
          float accf[4][8];
#pragma unroll
          for (int ks = 0; ks < 4; ++ks)
#pragma unroll
            for (int j = 0; j < 8; ++j) accf[ks][j] = 0.f;
          // rare tail (n>4): ~1.4% of rows
          if (__builtin_expect(n > 4, 0)) {
            const int2* op = ovf + (size_t)rowg * OVFS;
            i32x4 tr = *(const i32x4*)op;
            bool ok = n > 5;
            int sA = tr.x, sB = ok ? tr.z : 0;
            float cA = __int_as_float(tr.y), cB = ok ? __int_as_float(tr.w) : 0.f;
            const unsigned short* hA = hin + (size_t)sA * D + q * 8;
            const unsigned short* hB = hin + (size_t)sB * D + q * 8;
#pragma unroll
            for (int k2 = 0; k2 < 4; ++k2) {
              bf16x8 x0 = *(const bf16x8*)(hA + k2 * 32);
              bf16x8 x1 = *(const bf16x8*)(hB + k2 * 32);
#pragma unroll
              for (int j = 0; j < 8; ++j)
                accf[k2][j] += cA * bf2f((unsigned short)x0[j]) + cB * bf2f((unsigned short)x1[j]);
            }
            for (int i2 = 6; i2 < n; i2 += 2) {   // ultra-rare
              i32x4 rr = *(const i32x4*)(op + (i2 - 4));
              bool o2 = (i2 + 1) < n;
              int t0 = rr.x, t1 = o2 ? rr.z : 0;
              float d0 = __int_as_float(rr.y), d1 = o2 ? __int_as_float(rr.w) : 0.f;
              const unsigned short* y0 = hin + (size_t)t0 * D + q * 8;
              const unsigned short* y1 = hin + (size_t)t1 * D + q * 8;
#pragma unroll
              for (int k2 = 0; k2 < 4; ++k2) {
                bf16x8 x0 = *(const bf16x8*)(y0 + k2 * 32);
                bf16x8 x1 = *(const bf16x8*)(y1 + k2 * 32);
#pragma unroll
                for (int j = 0; j < 8; ++j)
                  accf[k2][j] += d0 * bf2f((unsigned short)x0[j]) + d1 * bf2f((unsigned short)x1[j]);
              }
            }
          }
          // main accumulate (named vars, static)
#pragma unroll
          for (int j = 0; j < 8; ++j) {
            accf[0][j] += c0 * bf2f((unsigned short)g0[j]) + c1 * bf2f((unsigned short)g4[j])
                        + c2 * bf2f((unsigned short)g8[j]) + c3 * bf2f((unsigned short)g12[j]);
            accf[1][j] += c0 * bf2f((unsigned short)g1[j]) + c1 * bf2f((unsigned short)g5[j])
                        + c2 * bf2f((unsigned short)g9[j]) + c3 * bf2f((unsigned short)g13[j]);
            accf[2][j] += c0 * bf2f((unsigned short)g2[j]) + c1 * bf2f((unsigned short)g6[j])
                        + c2 * bf2f((unsigned short)g10[j]) + c3 * bf2f((unsigned short)g14[j]);
            accf[3][j] += c0 * bf2f((unsigned short)g3[j]) + c1 * bf2f((unsigned short)g7[j])
                        + c2 * bf2f((unsigned short)g11[j]) + c3 * bf2f((unsigned short)g15[j]);
          }
          unsigned short* dstp = &t_lds[it & 1][(((r * 4) << 6) + lane) * 8];
#pragma unroll
          for (int ks = 0; ks < 4; ++ks) {
            union { bf16x8 v; unsigned short s[8]; } u;
#pragma unroll
            for (int j = 0; j < 8; ++j) u.s[j] = f2bf(accf[ks][j]);
            *(bf16x8*)(dstp + (ks << 6) * 8) = u.v;
          }
        }
        __syncthreads();
      }
    } else {
      // -------------------- consumer: cols [cw*32, cw*32+32) --------------------
      const int cw = w - 4;
      bf16x8 breg[R][4][2];
#pragma unroll
      for (int r2 = 0; r2 < R; ++r2) {
        const unsigned short* wr = Wt + ((size_t)(L * R + r2) << 14);
#pragma unroll
        for (int ks = 0; ks < 4; ++ks)
#pragma unroll
          for (int c = 0; c < 2; ++c) {
            int ct = cw * 2 + c;
            breg[r2][ks][c] = *(const bf16x8*)(wr + ((ct * 16 + m) << 7) + ks * 32 + q * 8);
          }
      }
      for (int it = 0; it < nt + 1; ++it) {
        if (it > 0) {
          const int tile = bid + (it - 1) * GRID;
          const int pb = (it - 1) & 1;
          float oacc[2][4];
#pragma unroll
          for (int c = 0; c < 2; ++c)
#pragma unroll
            for (int i = 0; i < 4; ++i) oacc[c][i] = 0.f;
#pragma unroll
          for (int r2 = 0; r2 < R; ++r2) {
            f32x4 acc2[2];
#pragma unroll
            for (int c = 0; c < 2; ++c) acc2[c] = (f32x4){0.f, 0.f, 0.f, 0.f};
#pragma unroll
            for (int ks = 0; ks < 4; ++ks) {
              bf16x8 a = *(const bf16x8*)&t_lds[pb][(((r2 * 4 + ks) << 6) + lane) * 8];
#pragma unroll
              for (int c = 0; c < 2; ++c)
                acc2[c] = __builtin_amdgcn_mfma_f32_16x16x32_bf16(a, breg[r2][ks][c], acc2[c], 0, 0, 0);
            }
            // deg_in rsqrt inline from raw in-degree
            i32x4 ci = *(const i32x4*)(cnt + (size_t)r2 * N_NODES + tile * 16 + q * 4);
#pragma unroll
            for (int c = 0; c < 2; ++c)
#pragma unroll
              for (int i = 0; i < 4; ++i)
                oacc[c][i] += rsqrtf(fmaxf((float)ci[i], 1.0f)) * acc2[c][i];
          }
#pragma unroll
          for (int c = 0; c < 2; ++c) {
            int colx = (cw * 2 + c) * 16 + m;
            float bm = bmean[L * D + colx];
#pragma unroll
            for (int i = 0; i < 4; ++i) {
              int row = tile * 16 + q * 4 + i;
              float v = oacc[c][i] * 0.25f + bm;
              v = (v >= 0.f) ? v : 0.2f * v;
              if (L == 0) {
                hb2[(size_t)row * D + colx] = f2bf(v);
              } else {
                v += bf2f(hb2[(size_t)row * D + colx]);   // residual
                out[(size_t)row * D + colx] = v;
              }
            }
          }
        }
        __syncthreads();
      }
    }
    if (L == 0) grid.sync();   // hb2 fully written before layer-1 gathers
  }
}

extern "C" void kernel_launch(void* const* d_in, const int* in_sizes, int n_in,
                              void* d_out, int out_size, void* d_ws, size_t ws_size,
                              hipStream_t stream) {
  const float* emb    = (const float*)d_in[0];
  const float* W      = (const float*)d_in[1];
  const float* biases = (const float*)d_in[2];
  const int*   edges  = (const int*)d_in[3];
  float* out = (float*)d_out;
  char* ws = (char*)d_ws;

  size_t off = 0;
  auto alloc = [&](size_t bytes) { size_t o = off; off += (bytes + 255) & ~255ull; return o; };
  int* ints = (int*)(ws + alloc((size_t)2 * NROWS * 4));                 // [deg_i | cursor], kernel-zeroed
  int2* rec2 = (int2*)(ws + alloc((size_t)R * TILES * 16 * 4 * 8));      // 12.8 MB, masked
  int2* ovf  = (int2*)(ws + alloc((size_t)NROWS * OVFS * 8));            // 38.4 MB, masked
  unsigned short* hb  = (unsigned short*)(ws + alloc((size_t)N_NODES * D * 2));
  unsigned short* hb2 = (unsigned short*)(ws + alloc((size_t)N_NODES * D * 2));
  unsigned short* Wt  = (unsigned short*)(ws + alloc((size_t)LAYERS * R * D * D * 2));
  float* bmean = (float*)(ws + alloc((size_t)LAYERS * D * 4));
  (void)ws_size;

  // ONE dispatch: cooperative mega-kernel (prep phases + both layers inside)
  void* kargs[] = { (void*)&emb, (void*)&W, (void*)&biases, (void*)&edges,
                    (void*)&ints, (void*)&rec2, (void*)&ovf, (void*)&hb, (void*)&hb2,
                    (void*)&Wt, (void*)&bmean, (void*)&out };
  hipLaunchCooperativeKernel((void*)mega_kernel, dim3(GRID), dim3(TPB), kargs, 0, stream);
}

// Round 7
// 340.131 us; speedup vs baseline: 4.4340x; 1.3826x over previous
//
#include <hip/hip_runtime.h>
#include <cstdint>
#include <cstddef>

#define N_NODES 100000
#define D 128
#define R 4
#define NE 150000
#define LAYERS 2
#define NROWS (R * N_NODES)   // 400000
#define CAP 16                // max in-degree per (rel,dst); Poisson(1.5) -> P(>16) ~ 1e-12
#define OVFS 12               // overflow slots per row (CAP - 4 inline)
#define TILES (N_NODES / 16)  // 6250
#define GRID 256              // persistent: one block per CU
#define TPB 512               // 8 waves: 4 producers + 4 consumers

typedef __attribute__((ext_vector_type(8))) short bf16x8;
typedef __attribute__((ext_vector_type(4))) float f32x4;
typedef __attribute__((ext_vector_type(4))) int i32x4;
typedef __attribute__((ext_vector_type(4))) unsigned short u16x4;

__device__ __forceinline__ unsigned short f2bf(float x) {
  union { float f; unsigned int u; } v; v.f = x;
  unsigned int u = v.u;
  return (unsigned short)((u + 0x7fffu + ((u >> 16) & 1u)) >> 16);  // RNE
}
__device__ __forceinline__ float bf2f(unsigned short u) {
  union { unsigned int i; float f; } v; v.i = ((unsigned int)u) << 16;
  return v.f;
}

// ---- prep1: out-degree count + emb fp32->bf16 + Wt transpose + bmean ------
// Fat grid (12500 blocks) so the atomics and the 77 MB stream run at full
// occupancy (the R6 mega-kernel ran these at 8 waves/CU and lost ~140us).
__global__ void prep1_kernel(const float* __restrict__ emb, const float* __restrict__ W,
                             const float* __restrict__ biases, const int* __restrict__ edges,
                             int* __restrict__ deg_i, unsigned short* __restrict__ hb,
                             unsigned short* __restrict__ Wt, float* __restrict__ bmean) {
  int t = blockIdx.x * blockDim.x + threadIdx.x;
  if (t < N_NODES * D / 4) {
    f32x4 v = *(const f32x4*)(emb + (size_t)t * 4);
    u16x4 o;
#pragma unroll
    for (int j = 0; j < 4; ++j) o[j] = f2bf(v[j]);
    *(u16x4*)(hb + (size_t)t * 4) = o;
  }
  if (t < NE * R) {
    int r = t / NE;
    int e = t - r * NE;
    int src = edges[(size_t)(r * 2) * NE + e];
    atomicAdd(&deg_i[r * N_NODES + src], 1);
  }
  if (t < LAYERS * R * D * D) {
    int k = t & 127;
    int c = (t >> 7) & 127;
    int lr = t >> 14;
    Wt[((size_t)lr << 14) | (c << 7) | k] = f2bf(W[((size_t)lr << 14) | (k << 7) | c]);
  }
  if (t < LAYERS * D) {
    int l = t >> 7, cc = t & 127;
    float s = 0.f;
    for (int r = 0; r < R; ++r) s += biases[((size_t)l * R + r) * D + cc];
    bmean[t] = s * 0.25f;
  }
}

// fill padded edge records {src, rsqrt(deg_out[src])}; cursor counts in-degree.
// SoA: slots 0..3 packed per (rel,tile): rec2[r][tile][m][slot] -> the producer's
// 16 rec lanes read 512 contiguous bytes (8 fully-used lines; was 16 half-used).
// Slots 4..15 -> ovf[rowg][slot-4]. Neither zeroed: producer masks by cnt.
__global__ void fill_kernel(const int* __restrict__ edges, const int* __restrict__ deg_i,
                            int* __restrict__ cursor, int2* __restrict__ rec2,
                            int2* __restrict__ ovf) {
  int e = blockIdx.x * blockDim.x + threadIdx.x;
  int r = blockIdx.y;
  if (e >= NE) return;
  int src = edges[(size_t)(r * 2) * NE + e];
  int dst = edges[(size_t)(r * 2 + 1) * NE + e];
  float sc = rsqrtf(fmaxf((float)deg_i[r * N_NODES + src], 1.0f));
  int rowg = r * N_NODES + dst;
  int slot = atomicAdd(&cursor[rowg], 1);
  if (slot < 4) {
    rec2[(((size_t)(r * TILES + (dst >> 4)) * 16 + (dst & 15)) << 2) + slot] =
        make_int2(src, __float_as_int(sc));
  } else if (slot < CAP) {
    ovf[(size_t)rowg * OVFS + (slot - 4)] = make_int2(src, __float_as_int(sc));
  }
}

// ======== persistent producer/consumer fused kernel =========================
// EXACT R0 structure (proven 101us/layer, 104 VGPR, zero scratch): waves 0-3
// gather-aggregate relation w of tile it into t_lds[it&1]; waves 4-7 MFMA +
// epilogue of tile it-1 from t_lds[(it-1)&1], B-fragments in registers.
// One __syncthreads per tile. NO multi-stage register pipelines (R2/R3/R5
// all spilled to scratch at >128 VGPR demand); NO raw-barrier/sched_barrier
// (R4: +19us). Gather service rate ~24 cy/line/CU is the measured floor
// (R1: 2 blocks/CU null; R2-R6: all pipelining attempts null or worse).
__global__ __launch_bounds__(TPB, 2) void fused_kernel(
    const unsigned short* __restrict__ hb,     // [N][128] bf16
    const int2* __restrict__ rec2,             // [R][TILES][16][4] {src, s_out}
    const int2* __restrict__ ovf,              // [NROWS][OVFS] overflow records
    const int* __restrict__ cnt,               // [NROWS] in-degree (may exceed CAP)
    const unsigned short* __restrict__ Wt,     // layer: [R][128 col][128 k] bf16
    const float* __restrict__ bmean,           // [128]
    const unsigned short* __restrict__ resid_bf,
    float* __restrict__ out_f,
    unsigned short* __restrict__ out_bf) {
  __shared__ unsigned short t_lds[2][R * 4 * 64 * 8];  // 2 x 16 KB
  const int w = threadIdx.x >> 6;
  const int lane = threadIdx.x & 63;
  const int m = lane & 15;
  const int q = lane >> 4;
  const int bid = blockIdx.x;
  const int nt = (TILES - bid + GRID - 1) / GRID;   // tiles for this block

  if (w < 4) {
    // -------------------- producer: relation w --------------------
    const int r = w;
    for (int it = 0; it < nt + 1; ++it) {
      if (it < nt) {
        const int tile = bid + it * GRID;
        const int rowg = r * N_NODES + tile * 16 + m;
        const int2* rp = rec2 + (((size_t)(r * TILES + tile) * 16 + m) << 2);
        int n = cnt[rowg];
        n = (n > CAP) ? CAP : n;
        i32x4 r01 = *(const i32x4*)(rp);
        i32x4 r23 = *(const i32x4*)(rp + 2);
        int   srcs[4] = { r01.x, r01.z, r23.x, r23.z };
        float scs[4]  = { __int_as_float(r01.y), __int_as_float(r01.w),
                          __int_as_float(r23.y), __int_as_float(r23.w) };
        // rec pads are garbage (not zeroed): mask; row 0 stays L1-hot
#pragma unroll
        for (int e = 0; e < 4; ++e) {
          if (e >= n) { srcs[e] = 0; scs[e] = 0.f; }
        }
        float accf[4][8];
#pragma unroll
        for (int ks = 0; ks < 4; ++ks)
#pragma unroll
          for (int j = 0; j < 8; ++j) accf[ks][j] = 0.f;
#pragma unroll
        for (int e = 0; e < 4; ++e) {
          const unsigned short* hp = hb + (size_t)srcs[e] * D + q * 8;
#pragma unroll
          for (int ks = 0; ks < 4; ++ks) {
            bf16x8 a = *(const bf16x8*)(hp + ks * 32);
#pragma unroll
            for (int j = 0; j < 8; ++j)
              accf[ks][j] += scs[e] * bf2f((unsigned short)a[j]);
          }
        }
        if (__builtin_expect(n > 4, 0)) {   // rare tail from ovf (~1.4% of rows)
          const int2* op = ovf + (size_t)rowg * OVFS;
          for (int i = 4; i < n; i += 2) {
            i32x4 rr = *(const i32x4*)(op + (i - 4));
            bool pairOk = (i + 1) < n;
            int  sA = rr.x;
            int  sB = pairOk ? rr.z : 0;
            float c0 = __int_as_float(rr.y);
            float c1 = pairOk ? __int_as_float(rr.w) : 0.f;
            const unsigned short* h0 = hb + (size_t)sA * D + q * 8;
            const unsigned short* h1 = hb + (size_t)sB * D + q * 8;
#pragma unroll
            for (int ks = 0; ks < 4; ++ks) {
              bf16x8 a0 = *(const bf16x8*)(h0 + ks * 32);
              bf16x8 a1 = *(const bf16x8*)(h1 + ks * 32);
#pragma unroll
              for (int j = 0; j < 8; ++j)
                accf[ks][j] += c0 * bf2f((unsigned short)a0[j]) + c1 * bf2f((unsigned short)a1[j]);
            }
          }
        }
        unsigned short* dstp = &t_lds[it & 1][(((r * 4) << 6) + lane) * 8];
#pragma unroll
        for (int ks = 0; ks < 4; ++ks) {
          union { bf16x8 v; unsigned short s[8]; } u;
#pragma unroll
          for (int j = 0; j < 8; ++j) u.s[j] = f2bf(accf[ks][j]);
          *(bf16x8*)(dstp + (ks << 6) * 8) = u.v;
        }
      }
      __syncthreads();
    }
  } else {
    // -------------------- consumer: cols [cw*32, cw*32+32) --------------------
    const int cw = w - 4;
    bf16x8 breg[R][4][2];
#pragma unroll
    for (int r = 0; r < R; ++r) {
      const unsigned short* wr = Wt + ((size_t)r << 14);
#pragma unroll
      for (int ks = 0; ks < 4; ++ks)
#pragma unroll
        for (int c = 0; c < 2; ++c) {
          int ct = cw * 2 + c;
          breg[r][ks][c] = *(const bf16x8*)(wr + ((ct * 16 + m) << 7) + ks * 32 + q * 8);
        }
    }
    for (int it = 0; it < nt + 1; ++it) {
      if (it > 0) {
        const int tile = bid + (it - 1) * GRID;
        const int pb = (it - 1) & 1;
        float oacc[2][4];
#pragma unroll
        for (int c = 0; c < 2; ++c)
#pragma unroll
          for (int i = 0; i < 4; ++i) oacc[c][i] = 0.f;
#pragma unroll
        for (int r = 0; r < R; ++r) {
          f32x4 acc2[2];
#pragma unroll
          for (int c = 0; c < 2; ++c) acc2[c] = (f32x4){0.f, 0.f, 0.f, 0.f};
#pragma unroll
          for (int ks = 0; ks < 4; ++ks) {
            bf16x8 a = *(const bf16x8*)&t_lds[pb][(((r * 4 + ks) << 6) + lane) * 8];
#pragma unroll
            for (int c = 0; c < 2; ++c)
              acc2[c] = __builtin_amdgcn_mfma_f32_16x16x32_bf16(a, breg[r][ks][c], acc2[c], 0, 0, 0);
          }
          // deg_in rsqrt inline from raw in-degree (replaces the s_in array+pass)
          i32x4 ci = *(const i32x4*)(cnt + (size_t)r * N_NODES + tile * 16 + q * 4);
#pragma unroll
          for (int c = 0; c < 2; ++c)
#pragma unroll
            for (int i = 0; i < 4; ++i)
              oacc[c][i] += rsqrtf(fmaxf((float)ci[i], 1.0f)) * acc2[c][i];
        }
#pragma unroll
        for (int c = 0; c < 2; ++c) {
          int colx = (cw * 2 + c) * 16 + m;
          float bm = bmean[colx];
#pragma unroll
          for (int i = 0; i < 4; ++i) {
            int row = tile * 16 + q * 4 + i;
            float v = oacc[c][i] * 0.25f + bm;
            v = (v >= 0.f) ? v : 0.2f * v;
            if (resid_bf) v += bf2f(resid_bf[(size_t)row * D + colx]);
            if (out_f) out_f[(size_t)row * D + colx] = v;
            else       out_bf[(size_t)row * D + colx] = f2bf(v);
          }
        }
      }
      __syncthreads();
    }
  }
}

extern "C" void kernel_launch(void* const* d_in, const int* in_sizes, int n_in,
                              void* d_out, int out_size, void* d_ws, size_t ws_size,
                              hipStream_t stream) {
  const float* emb    = (const float*)d_in[0];
  const float* W      = (const float*)d_in[1];
  const float* biases = (const float*)d_in[2];
  const int*   edges  = (const int*)d_in[3];
  float* out = (float*)d_out;
  char* ws = (char*)d_ws;

  size_t off = 0;
  auto alloc = [&](size_t bytes) { size_t o = off; off += (bytes + 255) & ~255ull; return o; };
  // only the int arrays (deg_i | cursor) need zeroing -> 3.2 MB memset
  int* ints      = (int*)(ws + alloc((size_t)2 * NROWS * 4));   // [deg_i | cursor]
  int* deg_i     = ints;
  int* cursor    = ints + NROWS;
  size_t zero_bytes = off;
  int2* rec2     = (int2*)(ws + alloc((size_t)R * TILES * 16 * 4 * 8));  // 12.8 MB, NOT zeroed
  int2* ovf      = (int2*)(ws + alloc((size_t)NROWS * OVFS * 8));        // 38.4 MB, NOT zeroed
  unsigned short* hb  = (unsigned short*)(ws + alloc((size_t)N_NODES * D * 2));
  unsigned short* hb2 = (unsigned short*)(ws + alloc((size_t)N_NODES * D * 2));
  unsigned short* Wt  = (unsigned short*)(ws + alloc((size_t)LAYERS * R * D * D * 2));
  float* bmean   = (float*)(ws + alloc((size_t)LAYERS * D * 4));
  (void)ws_size;

  // ---- prep: memset -> prep1(count+conversions) -> fill (3 dispatches) ----
  hipMemsetAsync(ws, 0, zero_bytes, stream);
  prep1_kernel<<<(N_NODES * D / 4 + 255) / 256, 256, 0, stream>>>(
      emb, W, biases, edges, deg_i, hb, Wt, bmean);
  fill_kernel<<<dim3((NE + 255) / 256, R), 256, 0, stream>>>(edges, deg_i, cursor, rec2, ovf);

  // layer 0: emb(bf16) -> hb2(bf16), no residual
  fused_kernel<<<GRID, TPB, 0, stream>>>(
      hb, rec2, ovf, cursor, Wt, bmean, nullptr, nullptr, hb2);
  // layer 1: hb2 -> out(fp32), residual = hb2
  fused_kernel<<<GRID, TPB, 0, stream>>>(
      hb2, rec2, ovf, cursor, Wt + (size_t)R * D * D, bmean + D, hb2, out, nullptr);
}